// Round 2
// baseline (259.843 us; speedup 1.0000x reference)
//
#include <hip/hip_runtime.h>
#include <math.h>

// out[h][i][j] = |j - i| * m, m = alpha[h] if (i==0 || j==0)
//                               else gamma[h] if j > i
//                               else beta[h]  if j < i   (i==j -> dist=0, don't care)
//
// Grid-stride over rows: each block handles several full (h,i) rows so the
// per-row preamble (div/mod + alpha/beta/gamma loads) is amortized.
// float4 built from named scalars -> stays in VGPRs -> global_store_dwordx4.

__global__ __launch_bounds__(256) void bidirectional_alibi_kernel(
    const float* __restrict__ alpha,
    const float* __restrict__ beta,
    const float* __restrict__ gamma,
    float* __restrict__ out,
    int S, int rowsTotal)
{
    const int n4 = S >> 2;

    for (int row = blockIdx.x; row < rowsTotal; row += gridDim.x) {
        const int i = row % S;
        const int h = row / S;

        const float a = alpha[h];
        const float b = beta[h];
        const float g = gamma[h];

        const float fi   = (float)i;
        const bool  row0 = (i == 0);

        float4* rp = (float4*)(out + (size_t)row * (size_t)S);

        for (int t = threadIdx.x; t < n4; t += blockDim.x) {
            const int j0 = t << 2;

            float s0 = (j0     > i) ? g : b;
            float s1 = (j0 + 1 > i) ? g : b;
            float s2 = (j0 + 2 > i) ? g : b;
            float s3 = (j0 + 3 > i) ? g : b;
            if (row0)    { s0 = a; s1 = a; s2 = a; s3 = a; }
            if (j0 == 0)   s0 = a;   // j == 0 column

            const float4 v = make_float4(
                fabsf((float)(j0    ) - fi) * s0,
                fabsf((float)(j0 + 1) - fi) * s1,
                fabsf((float)(j0 + 2) - fi) * s2,
                fabsf((float)(j0 + 3) - fi) * s3);

            rp[t] = v;
        }
    }
}

extern "C" void kernel_launch(void* const* d_in, const int* in_sizes, int n_in,
                              void* d_out, int out_size, void* d_ws, size_t ws_size,
                              hipStream_t stream) {
    const float* alpha = (const float*)d_in[0];
    const float* beta  = (const float*)d_in[1];
    const float* gamma = (const float*)d_in[2];
    float* out = (float*)d_out;

    const int H = in_sizes[0];                       // 16
    const long long ss = (long long)out_size / H;    // S*S
    const int S = (int)(sqrt((double)ss) + 0.5);     // 2048

    const int rowsTotal = H * S;                     // 32768 rows
    int blocks = rowsTotal / 8;                      // ~8 rows per block
    if (blocks > rowsTotal) blocks = rowsTotal;
    if (blocks < 1) blocks = 1;

    bidirectional_alibi_kernel<<<blocks, 256, 0, stream>>>(alpha, beta, gamma, out,
                                                           S, rowsTotal);
}

// Round 3
// 259.545 us; speedup vs baseline: 1.0011x; 1.0011x over previous
//
#include <hip/hip_runtime.h>
#include <math.h>

// out[h][i][j] = |j - i| * m, m = alpha[h] if (i==0 || j==0)
//                               else gamma[h] if j > i
//                               else beta[h]  if j < i   (i==j -> dist=0)
//
// Sign-folded form: val = (j - i) * s with
//   s = g   for j > i          (j-i > 0)
//   s = -b  for j < i  (i>0)   ((j-i)<0, so (j-i)*-b = b*(i-j))
//   s = -a  for j == 0, i > 0  ((0-i)*-a = i*a)
//   s = a   for row i == 0     (j*a; j==0 gives 0 regardless)
// 4 VALU per element: sub, cmp, cndmask, mul.
//
// Grid: (S/ROWS_PER_BLOCK, H). alpha/beta/gamma loaded ONCE per block
// (no per-row div/mod, no repeated scalar loads). Each block writes
// ROWS_PER_BLOCK contiguous rows (64 KiB for S=2048).

#define ROWS_PER_BLOCK 8

__global__ __launch_bounds__(256) void bidirectional_alibi_kernel(
    const float* __restrict__ alpha,
    const float* __restrict__ beta,
    const float* __restrict__ gamma,
    float* __restrict__ out,
    int S)
{
    const int h = blockIdx.y;
    const float a = alpha[h];
    const float b = beta[h];
    const float g = gamma[h];

    const int i0 = blockIdx.x * ROWS_PER_BLOCK;
    const int n4 = S >> 2;

    #pragma unroll
    for (int r = 0; r < ROWS_PER_BLOCK; ++r) {
        const int i = i0 + r;
        if (i >= S) break;

        const float fi  = (float)i;
        const float mhi = (i == 0) ? a : g;   // multiplier where j >= i (d >= 0)
        const float mlo = -b;                 // multiplier where j <  i (d <  0)
        const float m0  = (i == 0) ? a : -a;  // multiplier at j == 0

        float4* rp = (float4*)(out + ((size_t)h * (size_t)S + (size_t)i) * (size_t)S);

        for (int t = threadIdx.x; t < n4; t += blockDim.x) {
            const int   j0 = t << 2;
            const float f0 = (float)j0;

            const float d0 = f0        - fi;
            const float d1 = f0 + 1.0f - fi;
            const float d2 = f0 + 2.0f - fi;
            const float d3 = f0 + 3.0f - fi;

            float s0 = (d0 > 0.0f) ? mhi : mlo;
            const float s1 = (d1 > 0.0f) ? mhi : mlo;
            const float s2 = (d2 > 0.0f) ? mhi : mlo;
            const float s3 = (d3 > 0.0f) ? mhi : mlo;
            if (j0 == 0) s0 = m0;   // j == 0 column

            rp[t] = make_float4(d0 * s0, d1 * s1, d2 * s2, d3 * s3);
        }
    }
}

extern "C" void kernel_launch(void* const* d_in, const int* in_sizes, int n_in,
                              void* d_out, int out_size, void* d_ws, size_t ws_size,
                              hipStream_t stream) {
    const float* alpha = (const float*)d_in[0];
    const float* beta  = (const float*)d_in[1];
    const float* gamma = (const float*)d_in[2];
    float* out = (float*)d_out;

    const int H = in_sizes[0];                       // 16
    const long long ss = (long long)out_size / H;    // S*S
    const int S = (int)(sqrt((double)ss) + 0.5);     // 2048

    dim3 grid((S + ROWS_PER_BLOCK - 1) / ROWS_PER_BLOCK, H);
    bidirectional_alibi_kernel<<<grid, 256, 0, stream>>>(alpha, beta, gamma, out, S);
}